// Round 3
// baseline (346.446 us; speedup 1.0000x reference)
//
#include <hip/hip_runtime.h>

// Round 10: revert to R8's 1-sample-per-wave (best locality, 82.5us), but make
// waves persistent over a chunk of 16 consecutive sorted samples and software-
// pipeline across samples: scalar params (perm/pre) prefetched 2 ahead via
// s_load (lgkm pipe), xyz prefetched 1 ahead on the vector pipe, issued AFTER
// the current sample's gathers so the gather consume waits at vmcnt(3) while
// the next xyz rides out its HBM latency. 2048 blocks = 8 blocks/CU exactly.
// R9's 4-samples/wave failed: compiler serialized the gathers (VGPR=32) and
// wave count fell 4x -> more latency-bound, 119us.

#define VOL_N 256
#define S_PSF 64
#define NBUCKET 4096   // 16x16x16 cells of 16^3 voxels
#define TBL_ELEMS (1 << 24)                  // 256^3 entries
#define TBL_BYTES ((size_t)TBL_ELEMS * 8)    // 128 MB

typedef float vf4 __attribute__((ext_vector_type(4)));
typedef _Float16 vh4 __attribute__((ext_vector_type(4)));
typedef _Float16 vh8 __attribute__((ext_vector_type(8)));

// ---- d_ws layout ----
// [0, TBL_BYTES)      fp16 quad table (if ws large enough)
// then ints: hist[4096] | offsets[4096] | perm[N]
// then floats (32B aligned): pre[N][8] = {icx,icy,icz,hx,hy,hz,0,0} sorted

__device__ __forceinline__ int bucket_of(const float* __restrict__ sg, int n) {
    int cx = min(max((int)sg[n * 3 + 0], 0), VOL_N - 1) >> 4;
    int cy = min(max((int)sg[n * 3 + 1], 0), VOL_N - 1) >> 4;
    int cz = min(max((int)sg[n * 3 + 2], 0), VOL_N - 1) >> 4;
    int m = 0;
    #pragma unroll
    for (int b = 0; b < 4; b++) {
        m |= (((cx >> b) & 1) << (3 * b))
           | (((cy >> b) & 1) << (3 * b + 1))
           | (((cz >> b) & 1) << (3 * b + 2));
    }
    return m;
}

__global__ void zero_hist_kernel(int* __restrict__ ws) {
    int i = blockIdx.x * blockDim.x + threadIdx.x;
    if (i < NBUCKET) ws[i] = 0;
}

__global__ void hist_kernel(const float* __restrict__ sg, int* __restrict__ ws, int N) {
    int n = blockIdx.x * blockDim.x + threadIdx.x;
    if (n >= N) return;
    atomicAdd(&ws[bucket_of(sg, n)], 1);
}

__global__ __launch_bounds__(1024) void scan_kernel(int* __restrict__ ws) {
    __shared__ int tmp[1024];
    const int t = threadIdx.x;
    int h0 = ws[t * 4 + 0], h1 = ws[t * 4 + 1], h2 = ws[t * 4 + 2], h3 = ws[t * 4 + 3];
    int s = h0 + h1 + h2 + h3;
    tmp[t] = s;
    __syncthreads();
    for (int off = 1; off < 1024; off <<= 1) {
        int v = (t >= off) ? tmp[t - off] : 0;
        __syncthreads();
        tmp[t] += v;
        __syncthreads();
    }
    int excl = tmp[t] - s;
    ws[NBUCKET + t * 4 + 0] = excl;
    ws[NBUCKET + t * 4 + 1] = excl + h0;
    ws[NBUCKET + t * 4 + 2] = excl + h0 + h1;
    ws[NBUCKET + t * 4 + 3] = excl + h0 + h1 + h2;
}

// Scatter + fused per-sample setup: rotated center (pre-scaled to voxel-index
// space) and half extents written at the SORTED position.
__global__ void scatter_kernel(const float* __restrict__ sg,
                               const float* __restrict__ ax,
                               const float* __restrict__ bound,
                               int* __restrict__ ws,
                               float* __restrict__ pre, int N) {
    int n = blockIdx.x * blockDim.x + threadIdx.x;
    if (n >= N) return;
    int b = bucket_of(sg, n);
    int pos = atomicAdd(&ws[NBUCKET + b], 1);
    ws[2 * NBUCKET + pos] = n;

    const float vx = ax[n * 6 + 0], vy = ax[n * 6 + 1], vz = ax[n * 6 + 2];
    const float tx = ax[n * 6 + 3], ty = ax[n * 6 + 4], tz = ax[n * 6 + 5];

    const float theta = sqrtf(vx * vx + vy * vy + vz * vz);
    const float kinv = 1.0f / fmaxf(theta, 1e-12f);
    const float kx = vx * kinv, ky = vy * kinv, kz = vz * kinv;
    const float ct = __cosf(theta), st = __sinf(theta);
    const float oc = 1.0f - ct;

    const float r00 = 1.0f + oc * (-(ky * ky + kz * kz));
    const float r01 = -st * kz + oc * kx * ky;
    const float r02 =  st * ky + oc * kx * kz;
    const float r10 =  st * kz + oc * kx * ky;
    const float r11 = 1.0f + oc * (-(kx * kx + kz * kz));
    const float r12 = -st * kx + oc * ky * kz;
    const float r20 = -st * ky + oc * kx * kz;
    const float r21 =  st * kx + oc * ky * kz;
    const float r22 = 1.0f + oc * (-(kx * kx + ky * ky));

    const float px = sg[n * 3 + 0] + tx;
    const float py = sg[n * 3 + 1] + ty;
    const float pz = sg[n * 3 + 2] + tz;

    const float cx = r00 * px + r01 * py + r02 * pz;
    const float cy = r10 * px + r11 * py + r12 * pz;
    const float cz = r20 * px + r21 * py + r22 * pz;

    const float hx = (bound[n * 6 + 3] - bound[n * 6 + 0]) * 0.5f;
    const float hy = (bound[n * 6 + 4] - bound[n * 6 + 1]) * 0.5f;
    const float hz = (bound[n * 6 + 5] - bound[n * 6 + 2]) * 0.5f;

    const float scale = (float)VOL_N / (float)(VOL_N - 1);
    float4 A = make_float4(cx * scale - 0.5f, cy * scale - 0.5f,
                           cz * scale - 0.5f, hx);
    float4 B = make_float4(hy, hz, 0.0f, 0.0f);
    *(float4*)(pre + (size_t)pos * 8)     = A;
    *(float4*)(pre + (size_t)pos * 8 + 4) = B;
}

// Build fp16 quad table tbl[z][y][x] = {v[y][x], v[y][x+1], v[y+1][x],
// v[y+1][x+1]} with x=255/y=255 neighbors duplicated.
__global__ __launch_bounds__(256) void build_quad_kernel(
    const float* __restrict__ vol, vh4* __restrict__ tbl) {
    const int t = blockIdx.x * 256 + threadIdx.x;   // [0, 256*256*128)
    const int x2 = (t & 127) << 1;
    const int y = (t >> 7) & 255;
    const int z = t >> 15;
    const float* r0 = vol + (z << 16) + (y << 8);
    const float* r1 = vol + (z << 16) + (min(y + 1, VOL_N - 1) << 8);
    const float2 a = *(const float2*)(r0 + x2);
    const float2 b = *(const float2*)(r1 + x2);
    const float a2 = (x2 == VOL_N - 2) ? a.y : r0[x2 + 2];
    const float b2 = (x2 == VOL_N - 2) ? b.y : r1[x2 + 2];

    union { vh8 h; vf4 f; } o;
    o.h = (vh8){(_Float16)a.x, (_Float16)a.y, (_Float16)b.x, (_Float16)b.y,
                (_Float16)a.y, (_Float16)a2,  (_Float16)b.y, (_Float16)b2};
    *(vf4*)(tbl + ((z << 16) + (y << 8) + x2)) = o.f;
}

// Persistent-wave pipelined sampler: each wave handles `chunk` consecutive
// sorted samples; 64 lanes = 64 PSF points of one sample per iteration.
template <bool USE_TBL>
__global__ __launch_bounds__(256, 8) void psf_sample_pipe_kernel(
    const float* __restrict__ vol,        // [256][256][256] (z,y,x)
    const vh4* __restrict__ tbl,          // fp16 quad table (USE_TBL)
    const float* __restrict__ invcov,     // [3][3]
    const float* __restrict__ xyz_psf,    // [N][64][3]
    const int* __restrict__ perm,         // sorted pos -> n
    const float* __restrict__ pre,        // [N][8] precomputed setup (sorted)
    float* __restrict__ out,              // [N]
    int N, int chunk)
{
    const int lane = threadIdx.x & 63;

    // XCD-contiguous swizzle: each XCD sweeps a contiguous sorted range
    int bid = blockIdx.x;
    const int nb = gridDim.x;
    if ((nb & 7) == 0) bid = (bid & 7) * (nb >> 3) + (bid >> 3);

    const int wid = __builtin_amdgcn_readfirstlane(
        bid * (int)(blockDim.x >> 6) + (int)(threadIdx.x >> 6));
    const int start = wid * chunk;
    if (start >= N) return;
    const int end = min(start + chunk, N);

    const float m00 = invcov[0], m01 = invcov[1], m02 = invcov[2];
    const float m10 = invcov[3], m11 = invcov[4], m12 = invcov[5];
    const float m20 = invcov[6], m21 = invcov[7], m22 = invcov[8];
    const float scale = (float)VOL_N / (float)(VOL_N - 1);

    // ---- scalar pipe prologue (s_loads: uniform indices) ----
    int n0 = perm[start];
    float4 A0 = *(const float4*)(pre + (size_t)start * 8);
    float4 B0 = *(const float4*)(pre + (size_t)start * 8 + 4);
    const int i1c = min(start + 1, end - 1);
    int n1 = perm[i1c];
    float4 A1 = *(const float4*)(pre + (size_t)i1c * 8);
    float4 B1 = *(const float4*)(pre + (size_t)i1c * 8 + 4);

    // ---- vector pipe prologue: xyz of first sample ----
    const float* pp0 = xyz_psf + (size_t)n0 * (S_PSF * 3) + lane * 3;
    float gx = __builtin_nontemporal_load(pp0 + 0);
    float gy = __builtin_nontemporal_load(pp0 + 1);
    float gz = __builtin_nontemporal_load(pp0 + 2);

    for (int i = start; i < end; ++i) {
        const int nout = n0;
        const float icx = A0.x, icy = A0.y, icz = A0.z;
        const float hx = A0.w, hy = B0.x, hz = B0.y;

        const float ox = gx * hx, oy = gy * hy, oz = gz * hz;
        const float ix = fmaf(ox, scale, icx);
        const float iy = fmaf(oy, scale, icy);
        const float iz = fmaf(oz, scale, icz);

        const float x0f = floorf(ix), y0f = floorf(iy), z0f = floorf(iz);
        const float fx = ix - x0f, fy = iy - y0f, fz = iz - z0f;
        const int x0 = (int)x0f, y0 = (int)y0f, z0 = (int)z0f;

        // validity folded into separable axis weights
        const float wx0 = ((unsigned)x0       < (unsigned)VOL_N) ? (1.0f - fx) : 0.0f;
        const float wx1 = ((unsigned)(x0 + 1) < (unsigned)VOL_N) ? fx          : 0.0f;
        const float wy0 = ((unsigned)y0       < (unsigned)VOL_N) ? (1.0f - fy) : 0.0f;
        const float wy1 = ((unsigned)(y0 + 1) < (unsigned)VOL_N) ? fy          : 0.0f;
        const float wz0 = ((unsigned)z0       < (unsigned)VOL_N) ? (1.0f - fz) : 0.0f;
        const float wz1 = ((unsigned)(z0 + 1) < (unsigned)VOL_N) ? fz          : 0.0f;

        float v000, v001, v010, v011, v100, v101, v110, v111;
        vh4 p0, p1;
        bool lox = false, loy = false;
        if (USE_TBL) {
            const int xg = min(max(x0, 0), VOL_N - 1);
            const int yg = min(max(y0, 0), VOL_N - 1);
            const int zg0 = min(max(z0, 0), VOL_N - 1);
            const int zg1 = min(max(z0 + 1, 0), VOL_N - 1);
            const int common = (yg << 8) + xg;
            p0 = tbl[(zg0 << 16) + common];   // issue gathers (i)
            p1 = tbl[(zg1 << 16) + common];
            lox = x0 < 0;
            loy = y0 < 0;
        } else {
            const int xc0 = min(max(x0, 0), VOL_N - 1);
            const int xc1 = min(max(x0 + 1, 0), VOL_N - 1);
            const int yc0 = min(max(y0, 0), VOL_N - 1);
            const int yc1 = min(max(y0 + 1, 0), VOL_N - 1);
            const int zc0 = min(max(z0, 0), VOL_N - 1);
            const int zc1 = min(max(z0 + 1, 0), VOL_N - 1);
            const int zo0 = zc0 << 16, zo1 = zc1 << 16;
            const int yo0 = yc0 << 8, yo1 = yc1 << 8;
            v000 = vol[zo0 + yo0 + xc0];
            v001 = vol[zo0 + yo0 + xc1];
            v010 = vol[zo0 + yo1 + xc0];
            v011 = vol[zo0 + yo1 + xc1];
            v100 = vol[zo1 + yo0 + xc0];
            v101 = vol[zo1 + yo0 + xc1];
            v110 = vol[zo1 + yo1 + xc0];
            v111 = vol[zo1 + yo1 + xc1];
        }

        // ---- rotate scalar pipe; prefetch i+2 params (s_load, lgkm) ----
        n0 = n1; A0 = A1; B0 = B1;
        const int i2c = min(i + 2, end - 1);
        n1 = perm[i2c];
        A1 = *(const float4*)(pre + (size_t)i2c * 8);
        B1 = *(const float4*)(pre + (size_t)i2c * 8 + 4);

        // ---- issue xyz(i+1) AFTER gathers(i): consume below waits vmcnt(3) ----
        const float* pp = xyz_psf + (size_t)n0 * (S_PSF * 3) + lane * 3;
        const float gxn = __builtin_nontemporal_load(pp + 0);
        const float gyn = __builtin_nontemporal_load(pp + 1);
        const float gzn = __builtin_nontemporal_load(pp + 2);

        if (USE_TBL) {
            // slots: {y0x0, y0x1, y1x0, y1x1}; hi-edges duplicate-baked.
            float s00 = p0.x, s01 = p0.y, s10 = p0.z, s11 = p0.w;
            float a01 = lox ? s00 : s01, a11 = lox ? s10 : s11;
            v000 = s00;                 v001 = a01;
            v010 = loy ? s00 : s10;     v011 = loy ? a01 : a11;
            s00 = p1.x; s01 = p1.y; s10 = p1.z; s11 = p1.w;
            a01 = lox ? s00 : s01; a11 = lox ? s10 : s11;
            v100 = s00;                 v101 = a01;
            v110 = loy ? s00 : s10;     v111 = loy ? a01 : a11;
        }

        // pure-FMA separable trilinear (masked weights zero invalid corners)
        const float r0 = fmaf(v001, wx1, v000 * wx0);
        const float r1 = fmaf(v011, wx1, v010 * wx0);
        const float r2 = fmaf(v101, wx1, v100 * wx0);
        const float r3 = fmaf(v111, wx1, v110 * wx0);
        const float s0 = fmaf(r1, wy1, r0 * wy0);
        const float s1 = fmaf(r3, wy1, r2 * wy0);
        const float acc = fmaf(s1, wz1, s0 * wz0);

        const float qx = fmaf(m00, ox, fmaf(m01, oy, m02 * oz));
        const float qy = fmaf(m10, ox, fmaf(m11, oy, m12 * oz));
        const float qz = fmaf(m20, ox, fmaf(m21, oy, m22 * oz));
        const float q = fmaf(ox, qx, fmaf(oy, qy, oz * qz));
        const float w = __expf(-0.5f * q);

        float num = acc * w;
        float den = w;
        #pragma unroll
        for (int m = 32; m >= 1; m >>= 1) {
            num += __shfl_xor(num, m, 64);
            den += __shfl_xor(den, m, 64);
        }
        if (lane == 0) out[nout] = num / den;

        gx = gxn; gy = gyn; gz = gzn;
    }
}

// Fallback (no workspace): one sample per wave, direct vol gathers.
__global__ __launch_bounds__(256, 4) void psf_sample_plain_kernel(
    const float* __restrict__ vol,
    const float* __restrict__ sampleGrid,
    const float* __restrict__ ax,
    const float* __restrict__ bound,
    const float* __restrict__ invcov,
    const float* __restrict__ xyz_psf,
    float* __restrict__ out,
    int N)
{
    const int lane = threadIdx.x & 63;
    const int i = blockIdx.x * (blockDim.x >> 6) + (threadIdx.x >> 6);
    if (i >= N) return;
    const int n = __builtin_amdgcn_readfirstlane(i);

    const float vx = ax[n * 6 + 0], vy = ax[n * 6 + 1], vz = ax[n * 6 + 2];
    const float tx = ax[n * 6 + 3], ty = ax[n * 6 + 4], tz = ax[n * 6 + 5];
    const float theta = sqrtf(vx * vx + vy * vy + vz * vz);
    const float kinv = 1.0f / fmaxf(theta, 1e-12f);
    const float kx = vx * kinv, ky = vy * kinv, kz = vz * kinv;
    const float ct = __cosf(theta), st = __sinf(theta);
    const float oc = 1.0f - ct;
    const float r00 = 1.0f + oc * (-(ky * ky + kz * kz));
    const float r01 = -st * kz + oc * kx * ky;
    const float r02 =  st * ky + oc * kx * kz;
    const float r10 =  st * kz + oc * kx * ky;
    const float r11 = 1.0f + oc * (-(kx * kx + kz * kz));
    const float r12 = -st * kx + oc * ky * kz;
    const float r20 = -st * ky + oc * kx * kz;
    const float r21 =  st * kx + oc * ky * kz;
    const float r22 = 1.0f + oc * (-(kx * kx + ky * ky));
    const float px = sampleGrid[n * 3 + 0] + tx;
    const float py = sampleGrid[n * 3 + 1] + ty;
    const float pz = sampleGrid[n * 3 + 2] + tz;
    const float scale = (float)VOL_N / (float)(VOL_N - 1);
    const float icx = (r00 * px + r01 * py + r02 * pz) * scale - 0.5f;
    const float icy = (r10 * px + r11 * py + r12 * pz) * scale - 0.5f;
    const float icz = (r20 * px + r21 * py + r22 * pz) * scale - 0.5f;
    const float hx = (bound[n * 6 + 3] - bound[n * 6 + 0]) * 0.5f;
    const float hy = (bound[n * 6 + 4] - bound[n * 6 + 1]) * 0.5f;
    const float hz = (bound[n * 6 + 5] - bound[n * 6 + 2]) * 0.5f;

    const float m00 = invcov[0], m01 = invcov[1], m02 = invcov[2];
    const float m10 = invcov[3], m11 = invcov[4], m12 = invcov[5];
    const float m20 = invcov[6], m21 = invcov[7], m22 = invcov[8];

    const int pbase = (n * S_PSF + lane) * 3;
    const float ox = xyz_psf[pbase + 0] * hx;
    const float oy = xyz_psf[pbase + 1] * hy;
    const float oz = xyz_psf[pbase + 2] * hz;

    const float ix = fmaf(ox, scale, icx);
    const float iy = fmaf(oy, scale, icy);
    const float iz = fmaf(oz, scale, icz);
    const float x0f = floorf(ix), y0f = floorf(iy), z0f = floorf(iz);
    const float fx = ix - x0f, fy = iy - y0f, fz = iz - z0f;
    const int x0 = (int)x0f, y0 = (int)y0f, z0 = (int)z0f;

    const float wx0 = ((unsigned)x0       < (unsigned)VOL_N) ? (1.0f - fx) : 0.0f;
    const float wx1 = ((unsigned)(x0 + 1) < (unsigned)VOL_N) ? fx          : 0.0f;
    const float wy0 = ((unsigned)y0       < (unsigned)VOL_N) ? (1.0f - fy) : 0.0f;
    const float wy1 = ((unsigned)(y0 + 1) < (unsigned)VOL_N) ? fy          : 0.0f;
    const float wz0 = ((unsigned)z0       < (unsigned)VOL_N) ? (1.0f - fz) : 0.0f;
    const float wz1 = ((unsigned)(z0 + 1) < (unsigned)VOL_N) ? fz          : 0.0f;

    const int xc0 = min(max(x0, 0), VOL_N - 1);
    const int xc1 = min(max(x0 + 1, 0), VOL_N - 1);
    const int yc0 = min(max(y0, 0), VOL_N - 1);
    const int yc1 = min(max(y0 + 1, 0), VOL_N - 1);
    const int zc0 = min(max(z0, 0), VOL_N - 1);
    const int zc1 = min(max(z0 + 1, 0), VOL_N - 1);
    const int zo0 = zc0 << 16, zo1 = zc1 << 16;
    const int yo0 = yc0 << 8, yo1 = yc1 << 8;
    const float v000 = vol[zo0 + yo0 + xc0];
    const float v001 = vol[zo0 + yo0 + xc1];
    const float v010 = vol[zo0 + yo1 + xc0];
    const float v011 = vol[zo0 + yo1 + xc1];
    const float v100 = vol[zo1 + yo0 + xc0];
    const float v101 = vol[zo1 + yo0 + xc1];
    const float v110 = vol[zo1 + yo1 + xc0];
    const float v111 = vol[zo1 + yo1 + xc1];

    const float r0 = fmaf(v001, wx1, v000 * wx0);
    const float r1 = fmaf(v011, wx1, v010 * wx0);
    const float r2 = fmaf(v101, wx1, v100 * wx0);
    const float r3 = fmaf(v111, wx1, v110 * wx0);
    const float s0 = fmaf(r1, wy1, r0 * wy0);
    const float s1 = fmaf(r3, wy1, r2 * wy0);
    const float acc = fmaf(s1, wz1, s0 * wz0);

    const float qx = fmaf(m00, ox, fmaf(m01, oy, m02 * oz));
    const float qy = fmaf(m10, ox, fmaf(m11, oy, m12 * oz));
    const float qz = fmaf(m20, ox, fmaf(m21, oy, m22 * oz));
    const float q = fmaf(ox, qx, fmaf(oy, qy, oz * qz));
    const float w = __expf(-0.5f * q);

    float num = acc * w;
    float den = w;
    #pragma unroll
    for (int m = 32; m >= 1; m >>= 1) {
        num += __shfl_xor(num, m, 64);
        den += __shfl_xor(den, m, 64);
    }
    if (lane == 0) out[n] = num / den;
}

extern "C" void kernel_launch(void* const* d_in, const int* in_sizes, int n_in,
                              void* d_out, int out_size, void* d_ws, size_t ws_size,
                              hipStream_t stream) {
    const float* x        = (const float*)d_in[0];
    const float* sg       = (const float*)d_in[1];
    const float* ax       = (const float*)d_in[2];
    const float* bound    = (const float*)d_in[3];
    const float* invcov   = (const float*)d_in[4];
    const float* xyz_psf  = (const float*)d_in[5];
    float* out            = (float*)d_out;

    const int N = in_sizes[1] / 3;           // sampleGrid is [N][3]
    const size_t sort_bytes = (size_t)(2 * NBUCKET + N) * sizeof(int);
    const size_t sort_pad   = (sort_bytes + 31) & ~(size_t)31;   // align pre to 32B
    const size_t pre_bytes  = (size_t)N * 8 * sizeof(float);

    const bool use_tbl  = ws_size >= TBL_BYTES + sort_pad + pre_bytes;
    const bool use_sort = use_tbl || ws_size >= sort_pad + pre_bytes;

    vh4* tbl = use_tbl ? (vh4*)d_ws : nullptr;
    char* base = (char*)d_ws + (use_tbl ? TBL_BYTES : 0);
    int* sort_ws = (int*)base;
    float* pre = (float*)(base + sort_pad);

    int* perm = nullptr;
    if (use_sort) {
        zero_hist_kernel<<<(NBUCKET + 255) / 256, 256, 0, stream>>>(sort_ws);
        hist_kernel<<<(N + 255) / 256, 256, 0, stream>>>(sg, sort_ws, N);
        scan_kernel<<<1, 1024, 0, stream>>>(sort_ws);
        scatter_kernel<<<(N + 255) / 256, 256, 0, stream>>>(sg, ax, bound, sort_ws, pre, N);
        perm = sort_ws + 2 * NBUCKET;
    }
    if (use_tbl) {
        build_quad_kernel<<<(VOL_N * VOL_N * VOL_N / 2) / 256, 256, 0, stream>>>(x, tbl);
    }

    if (use_sort) {
        // persistent waves: 2048 blocks x 4 waves = 8192 waves; each sweeps a
        // contiguous chunk of sorted samples (exactly 8 blocks/CU resident).
        const int nwaves = 8192;
        const int chunk = (N + nwaves - 1) / nwaves;
        dim3 block(256);
        dim3 grid(2048);
        if (use_tbl) {
            psf_sample_pipe_kernel<true><<<grid, block, 0, stream>>>(
                x, tbl, invcov, xyz_psf, perm, pre, out, N, chunk);
        } else {
            psf_sample_pipe_kernel<false><<<grid, block, 0, stream>>>(
                x, nullptr, invcov, xyz_psf, perm, pre, out, N, chunk);
        }
    } else {
        dim3 block(256);
        dim3 grid((N + 3) / 4);
        psf_sample_plain_kernel<<<grid, block, 0, stream>>>(
            x, sg, ax, bound, invcov, xyz_psf, out, N);
    }
}

// Round 4
// 328.223 us; speedup vs baseline: 1.0555x; 1.0555x over previous
//
#include <hip/hip_runtime.h>

// Round 11: R10's cross-sample software pipeline, but with STRIDED sample->wave
// mapping (i = wid + k*8192) instead of chunked. R10's chunked mapping made the
// 8192 concurrent waves touch all N samples at once -> instantaneous working
// set = full 128 MB table -> FETCH 396 MB, HBM-bound, 129us. Strided mapping
// makes iteration k's active samples the contiguous sorted window [kW,(k+1)W)
// (~8 MB of table, L2-resident), same as R8's footprint, while keeping the
// pipeline: perm/pre prefetched 2-ahead (scalar pipe), xyz 1-ahead (vector
// pipe, issued after the current gathers so consume waits at vmcnt(3)).

#define VOL_N 256
#define S_PSF 64
#define NBUCKET 4096   // 16x16x16 cells of 16^3 voxels
#define TBL_ELEMS (1 << 24)                  // 256^3 entries
#define TBL_BYTES ((size_t)TBL_ELEMS * 8)    // 128 MB

typedef float vf4 __attribute__((ext_vector_type(4)));
typedef _Float16 vh4 __attribute__((ext_vector_type(4)));
typedef _Float16 vh8 __attribute__((ext_vector_type(8)));

// ---- d_ws layout ----
// [0, TBL_BYTES)      fp16 quad table (if ws large enough)
// then ints: hist[4096] | offsets[4096] | perm[N]
// then floats (32B aligned): pre[N][8] = {icx,icy,icz,hx,hy,hz,0,0} sorted

__device__ __forceinline__ int bucket_of(const float* __restrict__ sg, int n) {
    int cx = min(max((int)sg[n * 3 + 0], 0), VOL_N - 1) >> 4;
    int cy = min(max((int)sg[n * 3 + 1], 0), VOL_N - 1) >> 4;
    int cz = min(max((int)sg[n * 3 + 2], 0), VOL_N - 1) >> 4;
    int m = 0;
    #pragma unroll
    for (int b = 0; b < 4; b++) {
        m |= (((cx >> b) & 1) << (3 * b))
           | (((cy >> b) & 1) << (3 * b + 1))
           | (((cz >> b) & 1) << (3 * b + 2));
    }
    return m;
}

__global__ void zero_hist_kernel(int* __restrict__ ws) {
    int i = blockIdx.x * blockDim.x + threadIdx.x;
    if (i < NBUCKET) ws[i] = 0;
}

__global__ void hist_kernel(const float* __restrict__ sg, int* __restrict__ ws, int N) {
    int n = blockIdx.x * blockDim.x + threadIdx.x;
    if (n >= N) return;
    atomicAdd(&ws[bucket_of(sg, n)], 1);
}

__global__ __launch_bounds__(1024) void scan_kernel(int* __restrict__ ws) {
    __shared__ int tmp[1024];
    const int t = threadIdx.x;
    int h0 = ws[t * 4 + 0], h1 = ws[t * 4 + 1], h2 = ws[t * 4 + 2], h3 = ws[t * 4 + 3];
    int s = h0 + h1 + h2 + h3;
    tmp[t] = s;
    __syncthreads();
    for (int off = 1; off < 1024; off <<= 1) {
        int v = (t >= off) ? tmp[t - off] : 0;
        __syncthreads();
        tmp[t] += v;
        __syncthreads();
    }
    int excl = tmp[t] - s;
    ws[NBUCKET + t * 4 + 0] = excl;
    ws[NBUCKET + t * 4 + 1] = excl + h0;
    ws[NBUCKET + t * 4 + 2] = excl + h0 + h1;
    ws[NBUCKET + t * 4 + 3] = excl + h0 + h1 + h2;
}

// Scatter + fused per-sample setup: rotated center (pre-scaled to voxel-index
// space) and half extents written at the SORTED position.
__global__ void scatter_kernel(const float* __restrict__ sg,
                               const float* __restrict__ ax,
                               const float* __restrict__ bound,
                               int* __restrict__ ws,
                               float* __restrict__ pre, int N) {
    int n = blockIdx.x * blockDim.x + threadIdx.x;
    if (n >= N) return;
    int b = bucket_of(sg, n);
    int pos = atomicAdd(&ws[NBUCKET + b], 1);
    ws[2 * NBUCKET + pos] = n;

    const float vx = ax[n * 6 + 0], vy = ax[n * 6 + 1], vz = ax[n * 6 + 2];
    const float tx = ax[n * 6 + 3], ty = ax[n * 6 + 4], tz = ax[n * 6 + 5];

    const float theta = sqrtf(vx * vx + vy * vy + vz * vz);
    const float kinv = 1.0f / fmaxf(theta, 1e-12f);
    const float kx = vx * kinv, ky = vy * kinv, kz = vz * kinv;
    const float ct = __cosf(theta), st = __sinf(theta);
    const float oc = 1.0f - ct;

    const float r00 = 1.0f + oc * (-(ky * ky + kz * kz));
    const float r01 = -st * kz + oc * kx * ky;
    const float r02 =  st * ky + oc * kx * kz;
    const float r10 =  st * kz + oc * kx * ky;
    const float r11 = 1.0f + oc * (-(kx * kx + kz * kz));
    const float r12 = -st * kx + oc * ky * kz;
    const float r20 = -st * ky + oc * kx * kz;
    const float r21 =  st * kx + oc * ky * kz;
    const float r22 = 1.0f + oc * (-(kx * kx + ky * ky));

    const float px = sg[n * 3 + 0] + tx;
    const float py = sg[n * 3 + 1] + ty;
    const float pz = sg[n * 3 + 2] + tz;

    const float cx = r00 * px + r01 * py + r02 * pz;
    const float cy = r10 * px + r11 * py + r12 * pz;
    const float cz = r20 * px + r21 * py + r22 * pz;

    const float hx = (bound[n * 6 + 3] - bound[n * 6 + 0]) * 0.5f;
    const float hy = (bound[n * 6 + 4] - bound[n * 6 + 1]) * 0.5f;
    const float hz = (bound[n * 6 + 5] - bound[n * 6 + 2]) * 0.5f;

    const float scale = (float)VOL_N / (float)(VOL_N - 1);
    float4 A = make_float4(cx * scale - 0.5f, cy * scale - 0.5f,
                           cz * scale - 0.5f, hx);
    float4 B = make_float4(hy, hz, 0.0f, 0.0f);
    *(float4*)(pre + (size_t)pos * 8)     = A;
    *(float4*)(pre + (size_t)pos * 8 + 4) = B;
}

// Build fp16 quad table tbl[z][y][x] = {v[y][x], v[y][x+1], v[y+1][x],
// v[y+1][x+1]} with x=255/y=255 neighbors duplicated.
__global__ __launch_bounds__(256) void build_quad_kernel(
    const float* __restrict__ vol, vh4* __restrict__ tbl) {
    const int t = blockIdx.x * 256 + threadIdx.x;   // [0, 256*256*128)
    const int x2 = (t & 127) << 1;
    const int y = (t >> 7) & 255;
    const int z = t >> 15;
    const float* r0 = vol + (z << 16) + (y << 8);
    const float* r1 = vol + (z << 16) + (min(y + 1, VOL_N - 1) << 8);
    const float2 a = *(const float2*)(r0 + x2);
    const float2 b = *(const float2*)(r1 + x2);
    const float a2 = (x2 == VOL_N - 2) ? a.y : r0[x2 + 2];
    const float b2 = (x2 == VOL_N - 2) ? b.y : r1[x2 + 2];

    union { vh8 h; vf4 f; } o;
    o.h = (vh8){(_Float16)a.x, (_Float16)a.y, (_Float16)b.x, (_Float16)b.y,
                (_Float16)a.y, (_Float16)a2,  (_Float16)b.y, (_Float16)b2};
    *(vf4*)(tbl + ((z << 16) + (y << 8) + x2)) = o.f;
}

// Strided persistent-wave pipelined sampler: wave `wid` handles sorted samples
// wid, wid+W, wid+2W, ... so iteration k's concurrent samples are the
// contiguous sorted window [kW,(k+1)W) -> L2-resident table footprint.
template <bool USE_TBL>
__global__ __launch_bounds__(256, 8) void psf_sample_pipe_kernel(
    const float* __restrict__ vol,        // [256][256][256] (z,y,x)
    const vh4* __restrict__ tbl,          // fp16 quad table (USE_TBL)
    const float* __restrict__ invcov,     // [3][3]
    const float* __restrict__ xyz_psf,    // [N][64][3]
    const int* __restrict__ perm,         // sorted pos -> n
    const float* __restrict__ pre,        // [N][8] precomputed setup (sorted)
    float* __restrict__ out,              // [N]
    int N, int W)                         // W = total waves
{
    const int lane = threadIdx.x & 63;

    // XCD-contiguous swizzle: each XCD's waves form a contiguous wid range,
    // hence a contiguous slice of every window [kW,(k+1)W).
    int bid = blockIdx.x;
    const int nb = gridDim.x;
    if ((nb & 7) == 0) bid = (bid & 7) * (nb >> 3) + (bid >> 3);

    const int wid = __builtin_amdgcn_readfirstlane(
        bid * (int)(blockDim.x >> 6) + (int)(threadIdx.x >> 6));
    if (wid >= N) return;

    const float m00 = invcov[0], m01 = invcov[1], m02 = invcov[2];
    const float m10 = invcov[3], m11 = invcov[4], m12 = invcov[5];
    const float m20 = invcov[6], m21 = invcov[7], m22 = invcov[8];
    const float scale = (float)VOL_N / (float)(VOL_N - 1);

    // ---- scalar pipe prologue (s_loads: uniform indices) ----
    int n0 = perm[wid];
    float4 A0 = *(const float4*)(pre + (size_t)wid * 8);
    float4 B0 = *(const float4*)(pre + (size_t)wid * 8 + 4);
    const int i1c = (wid + W < N) ? (wid + W) : wid;
    int n1 = perm[i1c];
    float4 A1 = *(const float4*)(pre + (size_t)i1c * 8);
    float4 B1 = *(const float4*)(pre + (size_t)i1c * 8 + 4);

    // ---- vector pipe prologue: xyz of first sample ----
    const float* pp0 = xyz_psf + (size_t)n0 * (S_PSF * 3) + lane * 3;
    float gx = __builtin_nontemporal_load(pp0 + 0);
    float gy = __builtin_nontemporal_load(pp0 + 1);
    float gz = __builtin_nontemporal_load(pp0 + 2);

    for (int i = wid; i < N; i += W) {
        const int nout = n0;
        const float icx = A0.x, icy = A0.y, icz = A0.z;
        const float hx = A0.w, hy = B0.x, hz = B0.y;

        const float ox = gx * hx, oy = gy * hy, oz = gz * hz;
        const float ix = fmaf(ox, scale, icx);
        const float iy = fmaf(oy, scale, icy);
        const float iz = fmaf(oz, scale, icz);

        const float x0f = floorf(ix), y0f = floorf(iy), z0f = floorf(iz);
        const float fx = ix - x0f, fy = iy - y0f, fz = iz - z0f;
        const int x0 = (int)x0f, y0 = (int)y0f, z0 = (int)z0f;

        // validity folded into separable axis weights
        const float wx0 = ((unsigned)x0       < (unsigned)VOL_N) ? (1.0f - fx) : 0.0f;
        const float wx1 = ((unsigned)(x0 + 1) < (unsigned)VOL_N) ? fx          : 0.0f;
        const float wy0 = ((unsigned)y0       < (unsigned)VOL_N) ? (1.0f - fy) : 0.0f;
        const float wy1 = ((unsigned)(y0 + 1) < (unsigned)VOL_N) ? fy          : 0.0f;
        const float wz0 = ((unsigned)z0       < (unsigned)VOL_N) ? (1.0f - fz) : 0.0f;
        const float wz1 = ((unsigned)(z0 + 1) < (unsigned)VOL_N) ? fz          : 0.0f;

        float v000, v001, v010, v011, v100, v101, v110, v111;
        vh4 p0, p1;
        bool lox = false, loy = false;
        if (USE_TBL) {
            const int xg = min(max(x0, 0), VOL_N - 1);
            const int yg = min(max(y0, 0), VOL_N - 1);
            const int zg0 = min(max(z0, 0), VOL_N - 1);
            const int zg1 = min(max(z0 + 1, 0), VOL_N - 1);
            const int common = (yg << 8) + xg;
            p0 = tbl[(zg0 << 16) + common];   // issue gathers (i)
            p1 = tbl[(zg1 << 16) + common];
            lox = x0 < 0;
            loy = y0 < 0;
        } else {
            const int xc0 = min(max(x0, 0), VOL_N - 1);
            const int xc1 = min(max(x0 + 1, 0), VOL_N - 1);
            const int yc0 = min(max(y0, 0), VOL_N - 1);
            const int yc1 = min(max(y0 + 1, 0), VOL_N - 1);
            const int zc0 = min(max(z0, 0), VOL_N - 1);
            const int zc1 = min(max(z0 + 1, 0), VOL_N - 1);
            const int zo0 = zc0 << 16, zo1 = zc1 << 16;
            const int yo0 = yc0 << 8, yo1 = yc1 << 8;
            v000 = vol[zo0 + yo0 + xc0];
            v001 = vol[zo0 + yo0 + xc1];
            v010 = vol[zo0 + yo1 + xc0];
            v011 = vol[zo0 + yo1 + xc1];
            v100 = vol[zo1 + yo0 + xc0];
            v101 = vol[zo1 + yo0 + xc1];
            v110 = vol[zo1 + yo1 + xc0];
            v111 = vol[zo1 + yo1 + xc1];
        }

        // ---- rotate scalar pipe; prefetch params for i+2W (s_load, lgkm) ----
        n0 = n1; A0 = A1; B0 = B1;
        const int i2 = i + 2 * W;
        const int i2c = (i2 < N) ? i2 : (N - 1);
        n1 = perm[i2c];
        A1 = *(const float4*)(pre + (size_t)i2c * 8);
        B1 = *(const float4*)(pre + (size_t)i2c * 8 + 4);

        // ---- issue xyz(i+W) AFTER gathers(i): consume below waits vmcnt(3) ----
        const float* pp = xyz_psf + (size_t)n0 * (S_PSF * 3) + lane * 3;
        const float gxn = __builtin_nontemporal_load(pp + 0);
        const float gyn = __builtin_nontemporal_load(pp + 1);
        const float gzn = __builtin_nontemporal_load(pp + 2);

        if (USE_TBL) {
            // slots: {y0x0, y0x1, y1x0, y1x1}; hi-edges duplicate-baked.
            float s00 = p0.x, s01 = p0.y, s10 = p0.z, s11 = p0.w;
            float a01 = lox ? s00 : s01, a11 = lox ? s10 : s11;
            v000 = s00;                 v001 = a01;
            v010 = loy ? s00 : s10;     v011 = loy ? a01 : a11;
            s00 = p1.x; s01 = p1.y; s10 = p1.z; s11 = p1.w;
            a01 = lox ? s00 : s01; a11 = lox ? s10 : s11;
            v100 = s00;                 v101 = a01;
            v110 = loy ? s00 : s10;     v111 = loy ? a01 : a11;
        }

        // pure-FMA separable trilinear (masked weights zero invalid corners)
        const float r0 = fmaf(v001, wx1, v000 * wx0);
        const float r1 = fmaf(v011, wx1, v010 * wx0);
        const float r2 = fmaf(v101, wx1, v100 * wx0);
        const float r3 = fmaf(v111, wx1, v110 * wx0);
        const float s0 = fmaf(r1, wy1, r0 * wy0);
        const float s1 = fmaf(r3, wy1, r2 * wy0);
        const float acc = fmaf(s1, wz1, s0 * wz0);

        const float qx = fmaf(m00, ox, fmaf(m01, oy, m02 * oz));
        const float qy = fmaf(m10, ox, fmaf(m11, oy, m12 * oz));
        const float qz = fmaf(m20, ox, fmaf(m21, oy, m22 * oz));
        const float q = fmaf(ox, qx, fmaf(oy, qy, oz * qz));
        const float w = __expf(-0.5f * q);

        float num = acc * w;
        float den = w;
        #pragma unroll
        for (int m = 32; m >= 1; m >>= 1) {
            num += __shfl_xor(num, m, 64);
            den += __shfl_xor(den, m, 64);
        }
        if (lane == 0) out[nout] = num / den;

        gx = gxn; gy = gyn; gz = gzn;
    }
}

// Fallback (no workspace): one sample per wave, direct vol gathers.
__global__ __launch_bounds__(256, 4) void psf_sample_plain_kernel(
    const float* __restrict__ vol,
    const float* __restrict__ sampleGrid,
    const float* __restrict__ ax,
    const float* __restrict__ bound,
    const float* __restrict__ invcov,
    const float* __restrict__ xyz_psf,
    float* __restrict__ out,
    int N)
{
    const int lane = threadIdx.x & 63;
    const int i = blockIdx.x * (blockDim.x >> 6) + (threadIdx.x >> 6);
    if (i >= N) return;
    const int n = __builtin_amdgcn_readfirstlane(i);

    const float vx = ax[n * 6 + 0], vy = ax[n * 6 + 1], vz = ax[n * 6 + 2];
    const float tx = ax[n * 6 + 3], ty = ax[n * 6 + 4], tz = ax[n * 6 + 5];
    const float theta = sqrtf(vx * vx + vy * vy + vz * vz);
    const float kinv = 1.0f / fmaxf(theta, 1e-12f);
    const float kx = vx * kinv, ky = vy * kinv, kz = vz * kinv;
    const float ct = __cosf(theta), st = __sinf(theta);
    const float oc = 1.0f - ct;
    const float r00 = 1.0f + oc * (-(ky * ky + kz * kz));
    const float r01 = -st * kz + oc * kx * ky;
    const float r02 =  st * ky + oc * kx * kz;
    const float r10 =  st * kz + oc * kx * ky;
    const float r11 = 1.0f + oc * (-(kx * kx + kz * kz));
    const float r12 = -st * kx + oc * ky * kz;
    const float r20 = -st * ky + oc * kx * kz;
    const float r21 =  st * kx + oc * ky * kz;
    const float r22 = 1.0f + oc * (-(kx * kx + ky * ky));
    const float px = sampleGrid[n * 3 + 0] + tx;
    const float py = sampleGrid[n * 3 + 1] + ty;
    const float pz = sampleGrid[n * 3 + 2] + tz;
    const float scale = (float)VOL_N / (float)(VOL_N - 1);
    const float icx = (r00 * px + r01 * py + r02 * pz) * scale - 0.5f;
    const float icy = (r10 * px + r11 * py + r12 * pz) * scale - 0.5f;
    const float icz = (r20 * px + r21 * py + r22 * pz) * scale - 0.5f;
    const float hx = (bound[n * 6 + 3] - bound[n * 6 + 0]) * 0.5f;
    const float hy = (bound[n * 6 + 4] - bound[n * 6 + 1]) * 0.5f;
    const float hz = (bound[n * 6 + 5] - bound[n * 6 + 2]) * 0.5f;

    const float m00 = invcov[0], m01 = invcov[1], m02 = invcov[2];
    const float m10 = invcov[3], m11 = invcov[4], m12 = invcov[5];
    const float m20 = invcov[6], m21 = invcov[7], m22 = invcov[8];

    const int pbase = (n * S_PSF + lane) * 3;
    const float ox = xyz_psf[pbase + 0] * hx;
    const float oy = xyz_psf[pbase + 1] * hy;
    const float oz = xyz_psf[pbase + 2] * hz;

    const float ix = fmaf(ox, scale, icx);
    const float iy = fmaf(oy, scale, icy);
    const float iz = fmaf(oz, scale, icz);
    const float x0f = floorf(ix), y0f = floorf(iy), z0f = floorf(iz);
    const float fx = ix - x0f, fy = iy - y0f, fz = iz - z0f;
    const int x0 = (int)x0f, y0 = (int)y0f, z0 = (int)z0f;

    const float wx0 = ((unsigned)x0       < (unsigned)VOL_N) ? (1.0f - fx) : 0.0f;
    const float wx1 = ((unsigned)(x0 + 1) < (unsigned)VOL_N) ? fx          : 0.0f;
    const float wy0 = ((unsigned)y0       < (unsigned)VOL_N) ? (1.0f - fy) : 0.0f;
    const float wy1 = ((unsigned)(y0 + 1) < (unsigned)VOL_N) ? fy          : 0.0f;
    const float wz0 = ((unsigned)z0       < (unsigned)VOL_N) ? (1.0f - fz) : 0.0f;
    const float wz1 = ((unsigned)(z0 + 1) < (unsigned)VOL_N) ? fz          : 0.0f;

    const int xc0 = min(max(x0, 0), VOL_N - 1);
    const int xc1 = min(max(x0 + 1, 0), VOL_N - 1);
    const int yc0 = min(max(y0, 0), VOL_N - 1);
    const int yc1 = min(max(y0 + 1, 0), VOL_N - 1);
    const int zc0 = min(max(z0, 0), VOL_N - 1);
    const int zc1 = min(max(z0 + 1, 0), VOL_N - 1);
    const int zo0 = zc0 << 16, zo1 = zc1 << 16;
    const int yo0 = yc0 << 8, yo1 = yc1 << 8;
    const float v000 = vol[zo0 + yo0 + xc0];
    const float v001 = vol[zo0 + yo0 + xc1];
    const float v010 = vol[zo0 + yo1 + xc0];
    const float v011 = vol[zo0 + yo1 + xc1];
    const float v100 = vol[zo1 + yo0 + xc0];
    const float v101 = vol[zo1 + yo0 + xc1];
    const float v110 = vol[zo1 + yo1 + xc0];
    const float v111 = vol[zo1 + yo1 + xc1];

    const float r0 = fmaf(v001, wx1, v000 * wx0);
    const float r1 = fmaf(v011, wx1, v010 * wx0);
    const float r2 = fmaf(v101, wx1, v100 * wx0);
    const float r3 = fmaf(v111, wx1, v110 * wx0);
    const float s0 = fmaf(r1, wy1, r0 * wy0);
    const float s1 = fmaf(r3, wy1, r2 * wy0);
    const float acc = fmaf(s1, wz1, s0 * wz0);

    const float qx = fmaf(m00, ox, fmaf(m01, oy, m02 * oz));
    const float qy = fmaf(m10, ox, fmaf(m11, oy, m12 * oz));
    const float qz = fmaf(m20, ox, fmaf(m21, oy, m22 * oz));
    const float q = fmaf(ox, qx, fmaf(oy, qy, oz * qz));
    const float w = __expf(-0.5f * q);

    float num = acc * w;
    float den = w;
    #pragma unroll
    for (int m = 32; m >= 1; m >>= 1) {
        num += __shfl_xor(num, m, 64);
        den += __shfl_xor(den, m, 64);
    }
    if (lane == 0) out[n] = num / den;
}

extern "C" void kernel_launch(void* const* d_in, const int* in_sizes, int n_in,
                              void* d_out, int out_size, void* d_ws, size_t ws_size,
                              hipStream_t stream) {
    const float* x        = (const float*)d_in[0];
    const float* sg       = (const float*)d_in[1];
    const float* ax       = (const float*)d_in[2];
    const float* bound    = (const float*)d_in[3];
    const float* invcov   = (const float*)d_in[4];
    const float* xyz_psf  = (const float*)d_in[5];
    float* out            = (float*)d_out;

    const int N = in_sizes[1] / 3;           // sampleGrid is [N][3]
    const size_t sort_bytes = (size_t)(2 * NBUCKET + N) * sizeof(int);
    const size_t sort_pad   = (sort_bytes + 31) & ~(size_t)31;   // align pre to 32B
    const size_t pre_bytes  = (size_t)N * 8 * sizeof(float);

    const bool use_tbl  = ws_size >= TBL_BYTES + sort_pad + pre_bytes;
    const bool use_sort = use_tbl || ws_size >= sort_pad + pre_bytes;

    vh4* tbl = use_tbl ? (vh4*)d_ws : nullptr;
    char* base = (char*)d_ws + (use_tbl ? TBL_BYTES : 0);
    int* sort_ws = (int*)base;
    float* pre = (float*)(base + sort_pad);

    int* perm = nullptr;
    if (use_sort) {
        zero_hist_kernel<<<(NBUCKET + 255) / 256, 256, 0, stream>>>(sort_ws);
        hist_kernel<<<(N + 255) / 256, 256, 0, stream>>>(sg, sort_ws, N);
        scan_kernel<<<1, 1024, 0, stream>>>(sort_ws);
        scatter_kernel<<<(N + 255) / 256, 256, 0, stream>>>(sg, ax, bound, sort_ws, pre, N);
        perm = sort_ws + 2 * NBUCKET;
    }
    if (use_tbl) {
        build_quad_kernel<<<(VOL_N * VOL_N * VOL_N / 2) / 256, 256, 0, stream>>>(x, tbl);
    }

    if (use_sort) {
        // persistent waves, strided sweep: 2048 blocks x 4 waves = 8192 waves
        // (exactly 8 blocks/CU resident); W = wave count = window width.
        const int W = 8192;
        dim3 block(256);
        dim3 grid(2048);
        if (use_tbl) {
            psf_sample_pipe_kernel<true><<<grid, block, 0, stream>>>(
                x, tbl, invcov, xyz_psf, perm, pre, out, N, W);
        } else {
            psf_sample_pipe_kernel<false><<<grid, block, 0, stream>>>(
                x, nullptr, invcov, xyz_psf, perm, pre, out, N, W);
        }
    } else {
        dim3 block(256);
        dim3 grid((N + 3) / 4);
        psf_sample_plain_kernel<<<grid, block, 0, stream>>>(
            x, sg, ax, bound, invcov, xyz_psf, out, N);
    }
}

// Round 5
// 301.450 us; speedup vs baseline: 1.1493x; 1.0888x over previous
//
#include <hip/hip_runtime.h>

// Round 12: back to the R8 structure (one-shot dispatch, best locality,
// 82.5us psf) with ILP-2: each wave processes TWO consecutive sorted samples
// as independent straight-line streams. R8 was latency-bound (all pipes <40%);
// two interleaved chains double the work per latency exposure: xyzA+xyzB issue
// together, A's gathers overlap B's xyz return, A's consume waits with B's
// gathers in flight. Sorted-adjacent pairs share table cache lines.
// (R9-11 lessons: lane-splitting kills uniformity; persistent waves kill the
// dispatch-order locality that keeps the table L3/L2-resident.)

#define VOL_N 256
#define S_PSF 64
#define NBUCKET 4096   // 16x16x16 cells of 16^3 voxels
#define TBL_ELEMS (1 << 24)                  // 256^3 entries
#define TBL_BYTES ((size_t)TBL_ELEMS * 8)    // 128 MB

typedef float vf4 __attribute__((ext_vector_type(4)));
typedef _Float16 vh4 __attribute__((ext_vector_type(4)));
typedef _Float16 vh8 __attribute__((ext_vector_type(8)));

__device__ __forceinline__ int bucket_of(const float* __restrict__ sg, int n) {
    int cx = min(max((int)sg[n * 3 + 0], 0), VOL_N - 1) >> 4;
    int cy = min(max((int)sg[n * 3 + 1], 0), VOL_N - 1) >> 4;
    int cz = min(max((int)sg[n * 3 + 2], 0), VOL_N - 1) >> 4;
    int m = 0;
    #pragma unroll
    for (int b = 0; b < 4; b++) {
        m |= (((cx >> b) & 1) << (3 * b))
           | (((cy >> b) & 1) << (3 * b + 1))
           | (((cz >> b) & 1) << (3 * b + 2));
    }
    return m;
}

__global__ void zero_hist_kernel(int* __restrict__ ws) {
    int i = blockIdx.x * blockDim.x + threadIdx.x;
    if (i < NBUCKET) ws[i] = 0;
}

__global__ void hist_kernel(const float* __restrict__ sg, int* __restrict__ ws, int N) {
    int n = blockIdx.x * blockDim.x + threadIdx.x;
    if (n >= N) return;
    atomicAdd(&ws[bucket_of(sg, n)], 1);
}

__global__ __launch_bounds__(1024) void scan_kernel(int* __restrict__ ws) {
    __shared__ int tmp[1024];
    const int t = threadIdx.x;
    int h0 = ws[t * 4 + 0], h1 = ws[t * 4 + 1], h2 = ws[t * 4 + 2], h3 = ws[t * 4 + 3];
    int s = h0 + h1 + h2 + h3;
    tmp[t] = s;
    __syncthreads();
    for (int off = 1; off < 1024; off <<= 1) {
        int v = (t >= off) ? tmp[t - off] : 0;
        __syncthreads();
        tmp[t] += v;
        __syncthreads();
    }
    int excl = tmp[t] - s;
    ws[NBUCKET + t * 4 + 0] = excl;
    ws[NBUCKET + t * 4 + 1] = excl + h0;
    ws[NBUCKET + t * 4 + 2] = excl + h0 + h1;
    ws[NBUCKET + t * 4 + 3] = excl + h0 + h1 + h2;
}

__global__ void scatter_kernel(const float* __restrict__ sg,
                               const float* __restrict__ ax,
                               const float* __restrict__ bound,
                               int* __restrict__ ws,
                               float* __restrict__ pre, int N) {
    int n = blockIdx.x * blockDim.x + threadIdx.x;
    if (n >= N) return;
    int b = bucket_of(sg, n);
    int pos = atomicAdd(&ws[NBUCKET + b], 1);
    ws[2 * NBUCKET + pos] = n;

    const float vx = ax[n * 6 + 0], vy = ax[n * 6 + 1], vz = ax[n * 6 + 2];
    const float tx = ax[n * 6 + 3], ty = ax[n * 6 + 4], tz = ax[n * 6 + 5];

    const float theta = sqrtf(vx * vx + vy * vy + vz * vz);
    const float kinv = 1.0f / fmaxf(theta, 1e-12f);
    const float kx = vx * kinv, ky = vy * kinv, kz = vz * kinv;
    const float ct = __cosf(theta), st = __sinf(theta);
    const float oc = 1.0f - ct;

    const float r00 = 1.0f + oc * (-(ky * ky + kz * kz));
    const float r01 = -st * kz + oc * kx * ky;
    const float r02 =  st * ky + oc * kx * kz;
    const float r10 =  st * kz + oc * kx * ky;
    const float r11 = 1.0f + oc * (-(kx * kx + kz * kz));
    const float r12 = -st * kx + oc * ky * kz;
    const float r20 = -st * ky + oc * kx * kz;
    const float r21 =  st * kx + oc * ky * kz;
    const float r22 = 1.0f + oc * (-(kx * kx + ky * ky));

    const float px = sg[n * 3 + 0] + tx;
    const float py = sg[n * 3 + 1] + ty;
    const float pz = sg[n * 3 + 2] + tz;

    const float cx = r00 * px + r01 * py + r02 * pz;
    const float cy = r10 * px + r11 * py + r12 * pz;
    const float cz = r20 * px + r21 * py + r22 * pz;

    const float hx = (bound[n * 6 + 3] - bound[n * 6 + 0]) * 0.5f;
    const float hy = (bound[n * 6 + 4] - bound[n * 6 + 1]) * 0.5f;
    const float hz = (bound[n * 6 + 5] - bound[n * 6 + 2]) * 0.5f;

    const float scale = (float)VOL_N / (float)(VOL_N - 1);
    float4 A = make_float4(cx * scale - 0.5f, cy * scale - 0.5f,
                           cz * scale - 0.5f, hx);
    float4 B = make_float4(hy, hz, 0.0f, 0.0f);
    *(float4*)(pre + (size_t)pos * 8)     = A;
    *(float4*)(pre + (size_t)pos * 8 + 4) = B;
}

__global__ __launch_bounds__(256) void build_quad_kernel(
    const float* __restrict__ vol, vh4* __restrict__ tbl) {
    const int t = blockIdx.x * 256 + threadIdx.x;   // [0, 256*256*128)
    const int x2 = (t & 127) << 1;
    const int y = (t >> 7) & 255;
    const int z = t >> 15;
    const float* r0 = vol + (z << 16) + (y << 8);
    const float* r1 = vol + (z << 16) + (min(y + 1, VOL_N - 1) << 8);
    const float2 a = *(const float2*)(r0 + x2);
    const float2 b = *(const float2*)(r1 + x2);
    const float a2 = (x2 == VOL_N - 2) ? a.y : r0[x2 + 2];
    const float b2 = (x2 == VOL_N - 2) ? b.y : r1[x2 + 2];

    union { vh8 h; vf4 f; } o;
    o.h = (vh8){(_Float16)a.x, (_Float16)a.y, (_Float16)b.x, (_Float16)b.y,
                (_Float16)a.y, (_Float16)a2,  (_Float16)b.y, (_Float16)b2};
    *(vf4*)(tbl + ((z << 16) + (y << 8) + x2)) = o.f;
}

// ILP-2 sampler: each wave = two consecutive sorted samples, two independent
// dependency chains interleaved. One-shot dispatch (no persistence).
__global__ __launch_bounds__(256, 8) void psf_sample_du_kernel(
    const vh4* __restrict__ tbl,          // fp16 quad table
    const float* __restrict__ invcov,     // [3][3]
    const float* __restrict__ xyz_psf,    // [N][64][3]
    const int* __restrict__ perm,         // sorted pos -> n
    const float* __restrict__ pre,        // [N][8] precomputed setup (sorted)
    float* __restrict__ out,              // [N]
    int N)
{
    const int lane = threadIdx.x & 63;

    int bid = blockIdx.x;
    const int nb = gridDim.x;
    if ((nb & 7) == 0) bid = (bid & 7) * (nb >> 3) + (bid >> 3);

    const int wid = __builtin_amdgcn_readfirstlane(
        bid * (int)(blockDim.x >> 6) + (int)(threadIdx.x >> 6));
    const int iA = wid * 2;
    if (iA >= N) return;
    const bool hasB = (iA + 1) < N;
    const int iB = hasB ? (iA + 1) : iA;

    const int nA = __builtin_amdgcn_readfirstlane(perm[iA]);
    const int nB = __builtin_amdgcn_readfirstlane(perm[iB]);

    const float4 cA0 = *(const float4*)(pre + (size_t)iA * 8);
    const float4 cA1 = *(const float4*)(pre + (size_t)iA * 8 + 4);
    const float4 cB0 = *(const float4*)(pre + (size_t)iB * 8);
    const float4 cB1 = *(const float4*)(pre + (size_t)iB * 8 + 4);

    // ---- issue both xyz streams up front (independent HBM loads) ----
    const float* ppA = xyz_psf + (size_t)nA * (S_PSF * 3) + lane * 3;
    const float gxA = __builtin_nontemporal_load(ppA + 0);
    const float gyA = __builtin_nontemporal_load(ppA + 1);
    const float gzA = __builtin_nontemporal_load(ppA + 2);
    const float* ppB = xyz_psf + (size_t)nB * (S_PSF * 3) + lane * 3;
    const float gxB = __builtin_nontemporal_load(ppB + 0);
    const float gyB = __builtin_nontemporal_load(ppB + 1);
    const float gzB = __builtin_nontemporal_load(ppB + 2);

    const float m00 = invcov[0], m01 = invcov[1], m02 = invcov[2];
    const float m10 = invcov[3], m11 = invcov[4], m12 = invcov[5];
    const float m20 = invcov[6], m21 = invcov[7], m22 = invcov[8];
    const float scale = (float)VOL_N / (float)(VOL_N - 1);

    // ================= stream A: address + gathers =================
    const float oxA = gxA * cA0.w, oyA = gyA * cA1.x, ozA = gzA * cA1.y;
    const float ixA = fmaf(oxA, scale, cA0.x);
    const float iyA = fmaf(oyA, scale, cA0.y);
    const float izA = fmaf(ozA, scale, cA0.z);
    const float xA0f = floorf(ixA), yA0f = floorf(iyA), zA0f = floorf(izA);
    const float fxA = ixA - xA0f, fyA = iyA - yA0f, fzA = izA - zA0f;
    const int xA0 = (int)xA0f, yA0 = (int)yA0f, zA0 = (int)zA0f;

    const float wxA0 = ((unsigned)xA0       < (unsigned)VOL_N) ? (1.0f - fxA) : 0.0f;
    const float wxA1 = ((unsigned)(xA0 + 1) < (unsigned)VOL_N) ? fxA          : 0.0f;
    const float wyA0 = ((unsigned)yA0       < (unsigned)VOL_N) ? (1.0f - fyA) : 0.0f;
    const float wyA1 = ((unsigned)(yA0 + 1) < (unsigned)VOL_N) ? fyA          : 0.0f;
    const float wzA0 = ((unsigned)zA0       < (unsigned)VOL_N) ? (1.0f - fzA) : 0.0f;
    const float wzA1 = ((unsigned)(zA0 + 1) < (unsigned)VOL_N) ? fzA          : 0.0f;

    const int xgA  = min(max(xA0, 0), VOL_N - 1);
    const int ygA  = min(max(yA0, 0), VOL_N - 1);
    const int zgA0 = min(max(zA0, 0), VOL_N - 1);
    const int zgA1 = min(max(zA0 + 1, 0), VOL_N - 1);
    const int commonA = (ygA << 8) + xgA;
    const vh4 pA0 = tbl[(zgA0 << 16) + commonA];
    const vh4 pA1 = tbl[(zgA1 << 16) + commonA];
    const bool loxA = xA0 < 0, loyA = yA0 < 0;

    // ================= stream B: address + gathers =================
    const float oxB = gxB * cB0.w, oyB = gyB * cB1.x, ozB = gzB * cB1.y;
    const float ixB = fmaf(oxB, scale, cB0.x);
    const float iyB = fmaf(oyB, scale, cB0.y);
    const float izB = fmaf(ozB, scale, cB0.z);
    const float xB0f = floorf(ixB), yB0f = floorf(iyB), zB0f = floorf(izB);
    const float fxB = ixB - xB0f, fyB = iyB - yB0f, fzB = izB - zB0f;
    const int xB0 = (int)xB0f, yB0 = (int)yB0f, zB0 = (int)zB0f;

    const float wxB0 = ((unsigned)xB0       < (unsigned)VOL_N) ? (1.0f - fxB) : 0.0f;
    const float wxB1 = ((unsigned)(xB0 + 1) < (unsigned)VOL_N) ? fxB          : 0.0f;
    const float wyB0 = ((unsigned)yB0       < (unsigned)VOL_N) ? (1.0f - fyB) : 0.0f;
    const float wyB1 = ((unsigned)(yB0 + 1) < (unsigned)VOL_N) ? fyB          : 0.0f;
    const float wzB0 = ((unsigned)zB0       < (unsigned)VOL_N) ? (1.0f - fzB) : 0.0f;
    const float wzB1 = ((unsigned)(zB0 + 1) < (unsigned)VOL_N) ? fzB          : 0.0f;

    const int xgB  = min(max(xB0, 0), VOL_N - 1);
    const int ygB  = min(max(yB0, 0), VOL_N - 1);
    const int zgB0 = min(max(zB0, 0), VOL_N - 1);
    const int zgB1 = min(max(zB0 + 1, 0), VOL_N - 1);
    const int commonB = (ygB << 8) + xgB;
    const vh4 pB0 = tbl[(zgB0 << 16) + commonB];
    const vh4 pB1 = tbl[(zgB1 << 16) + commonB];
    const bool loxB = xB0 < 0, loyB = yB0 < 0;

    // ================= consume A =================
    float s00 = pA0.x, s01 = pA0.y, s10 = pA0.z, s11 = pA0.w;
    float a01 = loxA ? s00 : s01, a11 = loxA ? s10 : s11;
    const float vA000 = s00,                  vA001 = a01;
    const float vA010 = loyA ? s00 : s10,     vA011 = loyA ? a01 : a11;
    s00 = pA1.x; s01 = pA1.y; s10 = pA1.z; s11 = pA1.w;
    a01 = loxA ? s00 : s01; a11 = loxA ? s10 : s11;
    const float vA100 = s00,                  vA101 = a01;
    const float vA110 = loyA ? s00 : s10,     vA111 = loyA ? a01 : a11;

    const float rA0 = fmaf(vA001, wxA1, vA000 * wxA0);
    const float rA1 = fmaf(vA011, wxA1, vA010 * wxA0);
    const float rA2 = fmaf(vA101, wxA1, vA100 * wxA0);
    const float rA3 = fmaf(vA111, wxA1, vA110 * wxA0);
    const float sA0 = fmaf(rA1, wyA1, rA0 * wyA0);
    const float sA1 = fmaf(rA3, wyA1, rA2 * wyA0);
    const float accA = fmaf(sA1, wzA1, sA0 * wzA0);

    const float qxA = fmaf(m00, oxA, fmaf(m01, oyA, m02 * ozA));
    const float qyA = fmaf(m10, oxA, fmaf(m11, oyA, m12 * ozA));
    const float qzA = fmaf(m20, oxA, fmaf(m21, oyA, m22 * ozA));
    const float qA = fmaf(oxA, qxA, fmaf(oyA, qyA, ozA * qzA));
    const float wA = __expf(-0.5f * qA);
    float numA = accA * wA;
    float denA = wA;

    // ================= consume B =================
    s00 = pB0.x; s01 = pB0.y; s10 = pB0.z; s11 = pB0.w;
    a01 = loxB ? s00 : s01; a11 = loxB ? s10 : s11;
    const float vB000 = s00,                  vB001 = a01;
    const float vB010 = loyB ? s00 : s10,     vB011 = loyB ? a01 : a11;
    s00 = pB1.x; s01 = pB1.y; s10 = pB1.z; s11 = pB1.w;
    a01 = loxB ? s00 : s01; a11 = loxB ? s10 : s11;
    const float vB100 = s00,                  vB101 = a01;
    const float vB110 = loyB ? s00 : s10,     vB111 = loyB ? a01 : a11;

    const float rB0 = fmaf(vB001, wxB1, vB000 * wxB0);
    const float rB1 = fmaf(vB011, wxB1, vB010 * wxB0);
    const float rB2 = fmaf(vB101, wxB1, vB100 * wxB0);
    const float rB3 = fmaf(vB111, wxB1, vB110 * wxB0);
    const float sB0 = fmaf(rB1, wyB1, rB0 * wyB0);
    const float sB1 = fmaf(rB3, wyB1, rB2 * wyB0);
    const float accB = fmaf(sB1, wzB1, sB0 * wzB0);

    const float qxB = fmaf(m00, oxB, fmaf(m01, oyB, m02 * ozB));
    const float qyB = fmaf(m10, oxB, fmaf(m11, oyB, m12 * ozB));
    const float qzB = fmaf(m20, oxB, fmaf(m21, oyB, m22 * ozB));
    const float qB = fmaf(oxB, qxB, fmaf(oyB, qyB, ozB * qzB));
    const float wB = __expf(-0.5f * qB);
    float numB = accB * wB;
    float denB = wB;

    // ---- two independent butterfly reduces, interleaved ----
    #pragma unroll
    for (int m = 32; m >= 1; m >>= 1) {
        numA += __shfl_xor(numA, m, 64);
        numB += __shfl_xor(numB, m, 64);
        denA += __shfl_xor(denA, m, 64);
        denB += __shfl_xor(denB, m, 64);
    }
    if (lane == 0) {
        out[nA] = numA / denA;
        if (hasB) out[nB] = numB / denB;
    }
}

// Fallback (no workspace): one sample per wave, direct vol gathers.
__global__ __launch_bounds__(256, 4) void psf_sample_plain_kernel(
    const float* __restrict__ vol,
    const float* __restrict__ sampleGrid,
    const float* __restrict__ ax,
    const float* __restrict__ bound,
    const float* __restrict__ invcov,
    const float* __restrict__ xyz_psf,
    float* __restrict__ out,
    int N)
{
    const int lane = threadIdx.x & 63;
    const int i = blockIdx.x * (blockDim.x >> 6) + (threadIdx.x >> 6);
    if (i >= N) return;
    const int n = __builtin_amdgcn_readfirstlane(i);

    const float vx = ax[n * 6 + 0], vy = ax[n * 6 + 1], vz = ax[n * 6 + 2];
    const float tx = ax[n * 6 + 3], ty = ax[n * 6 + 4], tz = ax[n * 6 + 5];
    const float theta = sqrtf(vx * vx + vy * vy + vz * vz);
    const float kinv = 1.0f / fmaxf(theta, 1e-12f);
    const float kx = vx * kinv, ky = vy * kinv, kz = vz * kinv;
    const float ct = __cosf(theta), st = __sinf(theta);
    const float oc = 1.0f - ct;
    const float r00 = 1.0f + oc * (-(ky * ky + kz * kz));
    const float r01 = -st * kz + oc * kx * ky;
    const float r02 =  st * ky + oc * kx * kz;
    const float r10 =  st * kz + oc * kx * ky;
    const float r11 = 1.0f + oc * (-(kx * kx + kz * kz));
    const float r12 = -st * kx + oc * ky * kz;
    const float r20 = -st * ky + oc * kx * kz;
    const float r21 =  st * kx + oc * ky * kz;
    const float r22 = 1.0f + oc * (-(kx * kx + ky * ky));
    const float px = sampleGrid[n * 3 + 0] + tx;
    const float py = sampleGrid[n * 3 + 1] + ty;
    const float pz = sampleGrid[n * 3 + 2] + tz;
    const float scale = (float)VOL_N / (float)(VOL_N - 1);
    const float icx = (r00 * px + r01 * py + r02 * pz) * scale - 0.5f;
    const float icy = (r10 * px + r11 * py + r12 * pz) * scale - 0.5f;
    const float icz = (r20 * px + r21 * py + r22 * pz) * scale - 0.5f;
    const float hx = (bound[n * 6 + 3] - bound[n * 6 + 0]) * 0.5f;
    const float hy = (bound[n * 6 + 4] - bound[n * 6 + 1]) * 0.5f;
    const float hz = (bound[n * 6 + 5] - bound[n * 6 + 2]) * 0.5f;

    const float m00 = invcov[0], m01 = invcov[1], m02 = invcov[2];
    const float m10 = invcov[3], m11 = invcov[4], m12 = invcov[5];
    const float m20 = invcov[6], m21 = invcov[7], m22 = invcov[8];

    const int pbase = (n * S_PSF + lane) * 3;
    const float ox = xyz_psf[pbase + 0] * hx;
    const float oy = xyz_psf[pbase + 1] * hy;
    const float oz = xyz_psf[pbase + 2] * hz;

    const float ix = fmaf(ox, scale, icx);
    const float iy = fmaf(oy, scale, icy);
    const float iz = fmaf(oz, scale, icz);
    const float x0f = floorf(ix), y0f = floorf(iy), z0f = floorf(iz);
    const float fx = ix - x0f, fy = iy - y0f, fz = iz - z0f;
    const int x0 = (int)x0f, y0 = (int)y0f, z0 = (int)z0f;

    const float wx0 = ((unsigned)x0       < (unsigned)VOL_N) ? (1.0f - fx) : 0.0f;
    const float wx1 = ((unsigned)(x0 + 1) < (unsigned)VOL_N) ? fx          : 0.0f;
    const float wy0 = ((unsigned)y0       < (unsigned)VOL_N) ? (1.0f - fy) : 0.0f;
    const float wy1 = ((unsigned)(y0 + 1) < (unsigned)VOL_N) ? fy          : 0.0f;
    const float wz0 = ((unsigned)z0       < (unsigned)VOL_N) ? (1.0f - fz) : 0.0f;
    const float wz1 = ((unsigned)(z0 + 1) < (unsigned)VOL_N) ? fz          : 0.0f;

    const int xc0 = min(max(x0, 0), VOL_N - 1);
    const int xc1 = min(max(x0 + 1, 0), VOL_N - 1);
    const int yc0 = min(max(y0, 0), VOL_N - 1);
    const int yc1 = min(max(y0 + 1, 0), VOL_N - 1);
    const int zc0 = min(max(z0, 0), VOL_N - 1);
    const int zc1 = min(max(z0 + 1, 0), VOL_N - 1);
    const int zo0 = zc0 << 16, zo1 = zc1 << 16;
    const int yo0 = yc0 << 8, yo1 = yc1 << 8;
    const float v000 = vol[zo0 + yo0 + xc0];
    const float v001 = vol[zo0 + yo0 + xc1];
    const float v010 = vol[zo0 + yo1 + xc0];
    const float v011 = vol[zo0 + yo1 + xc1];
    const float v100 = vol[zo1 + yo0 + xc0];
    const float v101 = vol[zo1 + yo0 + xc1];
    const float v110 = vol[zo1 + yo1 + xc0];
    const float v111 = vol[zo1 + yo1 + xc1];

    const float r0 = fmaf(v001, wx1, v000 * wx0);
    const float r1 = fmaf(v011, wx1, v010 * wx0);
    const float r2 = fmaf(v101, wx1, v100 * wx0);
    const float r3 = fmaf(v111, wx1, v110 * wx0);
    const float s0 = fmaf(r1, wy1, r0 * wy0);
    const float s1 = fmaf(r3, wy1, r2 * wy0);
    const float acc = fmaf(s1, wz1, s0 * wz0);

    const float qx = fmaf(m00, ox, fmaf(m01, oy, m02 * oz));
    const float qy = fmaf(m10, ox, fmaf(m11, oy, m12 * oz));
    const float qz = fmaf(m20, ox, fmaf(m21, oy, m22 * oz));
    const float q = fmaf(ox, qx, fmaf(oy, qy, oz * qz));
    const float w = __expf(-0.5f * q);

    float num = acc * w;
    float den = w;
    #pragma unroll
    for (int m = 32; m >= 1; m >>= 1) {
        num += __shfl_xor(num, m, 64);
        den += __shfl_xor(den, m, 64);
    }
    if (lane == 0) out[n] = num / den;
}

extern "C" void kernel_launch(void* const* d_in, const int* in_sizes, int n_in,
                              void* d_out, int out_size, void* d_ws, size_t ws_size,
                              hipStream_t stream) {
    const float* x        = (const float*)d_in[0];
    const float* sg       = (const float*)d_in[1];
    const float* ax       = (const float*)d_in[2];
    const float* bound    = (const float*)d_in[3];
    const float* invcov   = (const float*)d_in[4];
    const float* xyz_psf  = (const float*)d_in[5];
    float* out            = (float*)d_out;

    const int N = in_sizes[1] / 3;           // sampleGrid is [N][3]
    const size_t sort_bytes = (size_t)(2 * NBUCKET + N) * sizeof(int);
    const size_t sort_pad   = (sort_bytes + 31) & ~(size_t)31;   // align pre to 32B
    const size_t pre_bytes  = (size_t)N * 8 * sizeof(float);

    const bool use_tbl = ws_size >= TBL_BYTES + sort_pad + pre_bytes;

    if (use_tbl) {
        vh4* tbl = (vh4*)d_ws;
        char* base = (char*)d_ws + TBL_BYTES;
        int* sort_ws = (int*)base;
        float* pre = (float*)(base + sort_pad);
        int* perm = sort_ws + 2 * NBUCKET;

        zero_hist_kernel<<<(NBUCKET + 255) / 256, 256, 0, stream>>>(sort_ws);
        hist_kernel<<<(N + 255) / 256, 256, 0, stream>>>(sg, sort_ws, N);
        scan_kernel<<<1, 1024, 0, stream>>>(sort_ws);
        scatter_kernel<<<(N + 255) / 256, 256, 0, stream>>>(sg, ax, bound, sort_ws, pre, N);
        build_quad_kernel<<<(VOL_N * VOL_N * VOL_N / 2) / 256, 256, 0, stream>>>(x, tbl);

        const int npair = (N + 1) / 2;
        dim3 block(256);
        dim3 grid((npair + 3) / 4);          // 8 samples per block (2/wave)
        psf_sample_du_kernel<<<grid, block, 0, stream>>>(
            tbl, invcov, xyz_psf, perm, pre, out, N);
    } else {
        dim3 block(256);
        dim3 grid((N + 3) / 4);
        psf_sample_plain_kernel<<<grid, block, 0, stream>>>(
            x, sg, ax, bound, invcov, xyz_psf, out, N);
    }
}